// Round 9
// baseline (65.672 us; speedup 1.0000x reference)
//
#include <hip/hip_runtime.h>
#include <hip/hip_fp16.h>

// Joint bilateral filter, K=5, zero padding. Guide t staged in LDS (f32),
// flow v read straight from global (L2/L3-cached), full-grid residency.
// t: (2,3,720,1280) f32; v: (2,2,720,1280) f32; out: (2,2,720,1280) f32
// coeff = max(0.875 - 50*sum_c (t_c - ts_c)^2, 0); out = sum(vs*coeff)/sum(coeff)
//
// Design: TLP-dominated kernel (R5/R6/R8 evidence). LDS 19,584 B (3 channels
// only) -> 8 blocks/CU; __launch_bounds__(256,8) caps VGPR at 64 -> all 1800
// blocks resident at once (2048 slots), no scheduling-round tail.
// v windows: 6 predicated coalesced float4/row from global; zero for OOB taps
// (= reference zero padding; den still accumulates coeff against staged ts=0).

constexpr int H_ = 720;
constexpr int W_ = 1280;
constexpr int HW = H_ * W_;
constexpr float COEF0 = 0.875f;  // 1 - |NEG_SS_DIV|
constexpr float SIDIV = 50.0f;   // 1/(2*0.1^2)

constexpr int TC = 136;          // staged cols (gx0-4 .. gx0+131), 16B-aligned
constexpr int TR = 12;           // staged rows (gy0-2 .. gy0+9)
constexpr int NCHUNK = 3 * TR * (TC / 4);   // 1224 float4 chunks; LDS byte = 16*i

__global__ __launch_bounds__(256, 8)
void jbf_tl(const float* __restrict__ t, const float* __restrict__ v,
            float* __restrict__ out) {
    __shared__ float lds[3][TR][TC];        // 19,584 B -> 8 blocks/CU

    const int bx = blockIdx.x % 10;         // 10 x-tiles of 128
    const int by = (blockIdx.x / 10) % 90;  // 90 y-tiles of 8
    const int n  = blockIdx.x / 900;        // 2 images
    const int gx0 = bx * 128;
    const int gy0 = by * 8;

    const float* tn = t + (size_t)n * 3 * HW;
    const float* vn = v + (size_t)n * 2 * HW;
    float*       on = out + (size_t)n * 2 * HW;

    const int tid = threadIdx.x;

    // ---------------- stage guide channels into LDS ----------------
#pragma unroll
    for (int it = 0; it < 5; ++it) {
        const int i = tid + it * 256;
        if (i < NCHUNK) {
            const int c4 = i % 34;           // col chunk (4 floats)
            const int rr = (i / 34) % TR;    // staged row
            const int ch = i / (34 * TR);    // 0..2 = t channels
            const int gy = gy0 - 2 + rr;
            const int gx = gx0 - 4 + 4 * c4; // multiple of 4 -> chunk all-in/out
            float4 val = make_float4(0.f, 0.f, 0.f, 0.f);
            if ((unsigned)gy < (unsigned)H_ && (unsigned)gx < (unsigned)(W_ - 3)) {
                val = *(const float4*)(tn + (size_t)ch * HW + gy * W_ + gx);
            }
            ((float4*)lds)[i] = val;         // byte 16*i == &lds[ch][rr][4*c4]
        }
    }
    __syncthreads();

    // ---------------- compute 4 px ----------------
    const int tx = tid & 31;                 // x-group within tile
    const int ty = tid >> 5;                 // output row within tile
    const int lc = 4 * tx;                   // window base col (k=0 <-> col lc)
    const int gxw = gx0 + lc - 4;            // global col of window base (mult of 4)

    // centers: staged row ty+2, cols lc+4..lc+7
    float c0f[4], c1f[4], c2f[4];
    *(float4*)c0f = *(const float4*)&lds[0][ty + 2][lc + 4];
    *(float4*)c1f = *(const float4*)&lds[1][ty + 2][lc + 4];
    *(float4*)c2f = *(const float4*)&lds[2][ty + 2][lc + 4];

    float num0[4] = {0.f, 0.f, 0.f, 0.f};
    float num1[4] = {0.f, 0.f, 0.f, 0.f};
    float den[4]  = {0.f, 0.f, 0.f, 0.f};

#pragma unroll 1
    for (int r = 0; r < 5; ++r) {
        const int lr = ty + r;                       // staged row
        const int gy = gy0 + ty + r - 2;             // global row
        const bool yin = (unsigned)gy < (unsigned)H_;
        const float* vr0 = vn + (size_t)gy * W_ + gxw;

        // v windows from global first (vmcnt overlaps the ds_reads below)
        float u0[12], u1[12];
#pragma unroll
        for (int s = 0; s < 3; ++s) {
            const bool in = yin && ((unsigned)(gxw + 4 * s) < (unsigned)(W_ - 3));
            float4 a = make_float4(0.f, 0.f, 0.f, 0.f);
            float4 b = make_float4(0.f, 0.f, 0.f, 0.f);
            if (in) {
                a = *(const float4*)(vr0 + 4 * s);
                b = *(const float4*)(vr0 + HW + 4 * s);
            }
            *(float4*)(u0 + 4 * s) = a;
            *(float4*)(u1 + 4 * s) = b;
        }

        // t windows from LDS (halo pre-zeroed at staging)
        float w0[12], w1[12], w2[12];
#pragma unroll
        for (int s = 0; s < 3; ++s) {
            *(float4*)(w0 + 4 * s) = *(const float4*)&lds[0][lr][lc + 4 * s];
            *(float4*)(w1 + 4 * s) = *(const float4*)&lds[1][lr][lc + 4 * s];
            *(float4*)(w2 + 4 * s) = *(const float4*)&lds[2][lr][lc + 4 * s];
        }

#pragma unroll
        for (int dx = 0; dx < 5; ++dx) {
#pragma unroll
            for (int j = 0; j < 4; ++j) {
                const int k = dx + j + 2;            // compile-time, k in [2,9]
                const float d0 = c0f[j] - w0[k];
                const float d1 = c1f[j] - w1[k];
                const float d2 = c2f[j] - w2[k];
                float diff = d0 * d0;
                diff = fmaf(d1, d1, diff);
                diff = fmaf(d2, d2, diff);
                const float c = fmaxf(fmaf(diff, -SIDIV, COEF0), 0.f);
                num0[j] = fmaf(u0[k], c, num0[j]);
                num1[j] = fmaf(u1[k], c, num1[j]);
                den[j] += c;
            }
        }
    }

    float4 o0, o1;
    float* o0a = (float*)&o0;
    float* o1a = (float*)&o1;
#pragma unroll
    for (int j = 0; j < 4; ++j) {
        const float rcp = 1.f / den[j];
        // mimic the reference's fp16 round-trip
        o0a[j] = __half2float(__float2half(num0[j] * rcp));
        o1a[j] = __half2float(__float2half(num1[j] * rcp));
    }
    const int ctr = (gy0 + ty) * W_ + gx0 + 4 * tx;
    *(float4*)(on + ctr) = o0;
    *(float4*)(on + HW + ctr) = o1;
}

extern "C" void kernel_launch(void* const* d_in, const int* in_sizes, int n_in,
                              void* d_out, int out_size, void* d_ws, size_t ws_size,
                              hipStream_t stream) {
    const float* t = (const float*)d_in[0];
    const float* v = (const float*)d_in[1];
    float* out = (float*)d_out;

    // 10 x-tiles * 90 y-tiles * 2 images = 1800 blocks of 256 (all resident)
    jbf_tl<<<1800, 256, 0, stream>>>(t, v, out);
}

// Round 10
// 30.870 us; speedup vs baseline: 2.1274x; 2.1274x over previous
//
#include <hip/hip_runtime.h>
#include <hip/hip_fp16.h>

// Joint bilateral filter, K=5, zero padding. f32 LDS tile with SHIFTED layout:
// staged col c <-> global col gx0-2+c, so each thread's 8-float tap window
// (k in [0,7] <-> global x-2..x+5) is two ALIGNED ds_read_b128 per channel.
// t: (2,3,720,1280) f32; v: (2,2,720,1280) f32; out: (2,2,720,1280) f32
// coeff = max(0.875 - 50*sum_c (t_c - ts_c)^2, 0); out = sum(vs*coeff)/sum(coeff)
//
// vs round 5 (best, 31.6us): DS reads 78 -> 50 b128/thread; centers extracted
// from the r=2 row's window (w[j+2]); staging splits each aligned global float4
// into two 8B-aligned float2 LDS writes to realize the 2-col shift.
// No launch_bounds min-waves (R6/R9 lesson: hint of 8 clamps VGPR to 32 + spill).

constexpr int H_ = 720;
constexpr int W_ = 1280;
constexpr int HW = H_ * W_;
constexpr float COEF0 = 0.875f;  // 1 - |NEG_SS_DIV|
constexpr float SIDIV = 50.0f;   // 1/(2*0.1^2)

constexpr int TC = 132;          // staged cols: global gx0-2 .. gx0+129
constexpr int TR = 12;           // staged rows: gy0-2 .. gy0+9
constexpr int NK = 34;           // aligned global chunks per row (gx0-4+4k, k=0..33)
constexpr int NCHUNK = 5 * TR * NK;   // 2040

// load one staged row's 8-wide windows (5 channels) into FRESH arrays in scope
#define LOADW(LR)                                                              \
    float w0[8], w1[8], w2[8], u0[8], u1[8];                                   \
    _Pragma("unroll") for (int s_ = 0; s_ < 2; ++s_) {                         \
        *(float4*)(w0 + 4 * s_) = *(const float4*)&lds[0][LR][lc + 4 * s_];    \
        *(float4*)(w1 + 4 * s_) = *(const float4*)&lds[1][LR][lc + 4 * s_];    \
        *(float4*)(w2 + 4 * s_) = *(const float4*)&lds[2][LR][lc + 4 * s_];    \
        *(float4*)(u0 + 4 * s_) = *(const float4*)&lds[3][LR][lc + 4 * s_];    \
        *(float4*)(u1 + 4 * s_) = *(const float4*)&lds[4][LR][lc + 4 * s_];    \
    }

// accumulate 5x4 taps; window elem m <-> global col x0w+m, tap k = dx+j in [0,7]
#define COMPW()                                                                \
    _Pragma("unroll") for (int dx_ = 0; dx_ < 5; ++dx_)                        \
        _Pragma("unroll") for (int j_ = 0; j_ < 4; ++j_) {                     \
            const int k_ = dx_ + j_;                                           \
            const float d0_ = c0f[j_] - w0[k_];                                \
            const float d1_ = c1f[j_] - w1[k_];                                \
            const float d2_ = c2f[j_] - w2[k_];                                \
            float diff_ = d0_ * d0_;                                           \
            diff_ = fmaf(d1_, d1_, diff_);                                     \
            diff_ = fmaf(d2_, d2_, diff_);                                     \
            const float c_ = fmaxf(fmaf(diff_, -SIDIV, COEF0), 0.f);           \
            num0[j_] = fmaf(u0[k_], c_, num0[j_]);                             \
            num1[j_] = fmaf(u1[k_], c_, num1[j_]);                             \
            den[j_] += c_;                                                     \
        }

__global__ __launch_bounds__(256)
void jbf_s(const float* __restrict__ t, const float* __restrict__ v,
           float* __restrict__ out) {
    __shared__ float lds[5][TR][TC];        // 31,680 B -> 5 blocks/CU

    const int bx = blockIdx.x % 10;         // 10 x-tiles of 128
    const int by = (blockIdx.x / 10) % 90;  // 90 y-tiles of 8
    const int n  = blockIdx.x / 900;        // 2 images
    const int gx0 = bx * 128;
    const int gy0 = by * 8;

    const float* tn = t + (size_t)n * 3 * HW;
    const float* vn = v + (size_t)n * 2 * HW;
    float*       on = out + (size_t)n * 2 * HW;

    const int tid = threadIdx.x;

    // ------- stage: aligned global float4 -> two 8B-aligned float2 LDS writes -------
#pragma unroll
    for (int it = 0; it < 8; ++it) {
        const int i = tid + it * 256;
        if (i < NCHUNK) {
            const int k  = i % NK;           // aligned chunk: global cols gx0-4+4k..+3
            const int rr = (i / NK) % TR;    // staged row
            const int ch = i / (NK * TR);    // 0..2 = t, 3..4 = v
            const int gy = gy0 - 2 + rr;
            const int gx = gx0 - 4 + 4 * k;
            float4 val = make_float4(0.f, 0.f, 0.f, 0.f);
            if ((unsigned)gy < (unsigned)H_ && (unsigned)gx < (unsigned)(W_ - 3)) {
                const float* src = (ch < 3) ? (tn + (size_t)ch * HW)
                                            : (vn + (size_t)(ch - 3) * HW);
                val = *(const float4*)(src + gy * W_ + gx);
            }
            // global cols gx..gx+3 <-> staged cols 4k-2 .. 4k+1
            float* row = &lds[ch][rr][0];
            if (k > 0)      *(float2*)&row[4 * k - 2] = make_float2(val.x, val.y);
            if (k < NK - 1) *(float2*)&row[4 * k]     = make_float2(val.z, val.w);
        }
    }
    __syncthreads();

    // ---------------- compute 4 px from LDS ----------------
    const int tx = tid & 31;                 // x-group within tile
    const int ty = tid >> 5;                 // output row within tile
    const int lc = 4 * tx;                   // window base staged col (global x0w = gx0+4tx-2)

    float c0f[4], c1f[4], c2f[4];
    float num0[4] = {0.f, 0.f, 0.f, 0.f};
    float num1[4] = {0.f, 0.f, 0.f, 0.f};
    float den[4]  = {0.f, 0.f, 0.f, 0.f};

    {   // r = 2 first: its window contains the centers (elem j+2 = pixel j)
        const int lr = ty + 2;
        LOADW(lr)
#pragma unroll
        for (int j = 0; j < 4; ++j) {
            c0f[j] = w0[j + 2];
            c1f[j] = w1[j + 2];
            c2f[j] = w2[j + 2];
        }
        COMPW()
    }
#pragma unroll 1
    for (int i = 0; i < 4; ++i) {
        const int r = i + (i >> 1);          // 0,1,3,4
        const int lr = ty + r;
        LOADW(lr)
        COMPW()
    }

    float4 o0, o1;
    float* o0a = (float*)&o0;
    float* o1a = (float*)&o1;
#pragma unroll
    for (int j = 0; j < 4; ++j) {
        const float rcp = 1.f / den[j];
        // mimic the reference's fp16 round-trip
        o0a[j] = __half2float(__float2half(num0[j] * rcp));
        o1a[j] = __half2float(__float2half(num1[j] * rcp));
    }
    const int ctr = (gy0 + ty) * W_ + gx0 + 4 * tx;
    *(float4*)(on + ctr) = o0;
    *(float4*)(on + HW + ctr) = o1;
}

extern "C" void kernel_launch(void* const* d_in, const int* in_sizes, int n_in,
                              void* d_out, int out_size, void* d_ws, size_t ws_size,
                              hipStream_t stream) {
    const float* t = (const float*)d_in[0];
    const float* v = (const float*)d_in[1];
    float* out = (float*)d_out;

    // 10 x-tiles * 90 y-tiles * 2 images = 1800 blocks of 256
    jbf_s<<<1800, 256, 0, stream>>>(t, v, out);
}